// Round 6
// baseline (1196.313 us; speedup 1.0000x reference)
//
#include <hip/hip_runtime.h>
#include <math.h>

static constexpr int BTOT = 32768;
static constexpr int IND  = 64;
static constexpr int HD   = 256;
static constexpr int LT   = 32;
static constexpr int NCH  = 8;
static constexpr int NCD  = 256;
static constexpr int TM   = 32;
static constexpr int NBLK = BTOT / TM;   // 1024

// workspace float offsets
static constexpr int WS_M    = 0;        // 8*256 folded score matrix M = cq@Wk
static constexpr int WS_C0   = 2048;     // 8 folded score bias c0 = cq@bk
static constexpr int WS_CSQ  = 2056;     // 8*256 codebook squared norms (np-pairwise fp32)
static constexpr int WS_PART = 4104;     // NBLK loss partials

// output float offsets
static constexpr long long O_KCHART = 0;
static constexpr long long O_KCODE  = 32768;
static constexpr long long O_ZN     = 65536;
static constexpr long long O_ZTEX   = 1114112;
static constexpr long long O_RW     = 2162688;
static constexpr long long O_ZGEO   = 2424832;
static constexpr long long O_VQ     = 3473408;
static constexpr long long O_IDX    = 3473409;
static constexpr long long O_ZNALL  = 3735553;

// LDS: 8192 floats = 32768 B exactly.
// GEMM phases use [0..8192) as x/h1/h2 buffer. VQ phase overlays:
static constexpr int L_CH  = 0;      // 4096: half-chart (128 codes x 32, swizzled)
static constexpr int L_VDL = 4096;   // 32 rows x stride 36: v, then delta
static constexpr int L_S1  = 5248;   // 32 rows x stride 20: s1 activations
static constexpr int L_W1  = 5888;   // 16 rows x stride 36: Ws1
static constexpr int L_W2  = 6464;   // 16 rows x stride 36: Ws2 TRANSPOSED (W2T[j][o])
static constexpr int L_B1  = 7040;   // 16
static constexpr int L_B2  = 7056;   // 32
static constexpr int L_MISC= 7088;   // 16: loss reduce scratch
static constexpr int LDS_F = 8192;

__device__ __forceinline__ float gelu_f(float x) {
    return 0.5f * x * (1.0f + erff(x * 0.70710678118654752f));
}
__device__ __forceinline__ float dot4(float4 a, float4 b) {
    return a.x * b.x + a.y * b.y + a.z * b.z + a.w * b.w;
}
// numpy pairwise_sum of squares, n=32 (8 accumulators, stride-8, fixed tree)
__device__ __forceinline__ float np_sumsq32(const float* a) {
#pragma clang fp contract(off)
    float r0 = a[0]*a[0],  r1 = a[1]*a[1],  r2 = a[2]*a[2],  r3 = a[3]*a[3];
    float r4 = a[4]*a[4],  r5 = a[5]*a[5],  r6 = a[6]*a[6],  r7 = a[7]*a[7];
    r0 += a[8]*a[8];   r1 += a[9]*a[9];   r2 += a[10]*a[10]; r3 += a[11]*a[11];
    r4 += a[12]*a[12]; r5 += a[13]*a[13]; r6 += a[14]*a[14]; r7 += a[15]*a[15];
    r0 += a[16]*a[16]; r1 += a[17]*a[17]; r2 += a[18]*a[18]; r3 += a[19]*a[19];
    r4 += a[20]*a[20]; r5 += a[21]*a[21]; r6 += a[22]*a[22]; r7 += a[23]*a[23];
    r0 += a[24]*a[24]; r1 += a[25]*a[25]; r2 += a[26]*a[26]; r3 += a[27]*a[27];
    r4 += a[28]*a[28]; r5 += a[29]*a[29]; r6 += a[30]*a[30]; r7 += a[31]*a[31];
    return ((r0 + r1) + (r2 + r3)) + ((r4 + r5) + (r6 + r7));
}

// ---------- prep: M = cq@Wk, c0 = cq@bk, c_sq ----------
__global__ __launch_bounds__(256) void prep_kernel(
    const float* __restrict__ Wk, const float* __restrict__ bk,
    const float* __restrict__ cq, const float* __restrict__ cb,
    float* __restrict__ ws)
{
    const int g = blockIdx.x;
    const int t = threadIdx.x;
    {
        const int n = t >> 5;
        const int j = (g << 5) + (t & 31);
        float acc = 0.f;
        for (int o = 0; o < HD; ++o)
            acc += cq[n * HD + o] * Wk[o * HD + j];
        ws[WS_M + n * HD + j] = acc;
    }
    {
        const float* p = cb + (long long)((g << 8) + t) * LT;
        float a[32];
#pragma unroll
        for (int d = 0; d < LT; ++d) a[d] = p[d];
        ws[WS_CSQ + (g << 8) + t] = np_sumsq32(a);
    }
    {
        float p = cq[g * HD + t] * bk[t];
#pragma unroll
        for (int off = 1; off < 64; off <<= 1) p += __shfl_xor(p, off, 64);
        __shared__ float red[4];
        if ((t & 63) == 0) red[t >> 6] = p;
        __syncthreads();
        if (t == 0) ws[WS_C0 + g] = red[0] + red[1] + red[2] + red[3];
    }
}

// ---------- main fused kernel ----------
// Plain __launch_bounds__(256): the (256,N) form collapses the VGPR budget
// (r3: 84, r4: 64) and spills. Target: VGPR<=128 + LDS 32768 -> 4 blocks/CU.
__global__ __launch_bounds__(256) void main_kernel(
    const float* __restrict__ x,  const float* __restrict__ W1, const float* __restrict__ b1,
    const float* __restrict__ W2, const float* __restrict__ b2,
    const float* __restrict__ Wv, const float* __restrict__ bv,
    const float* __restrict__ cb,
    const float* __restrict__ Ws1, const float* __restrict__ bs1,
    const float* __restrict__ Ws2, const float* __restrict__ bs2,
    const float* __restrict__ ws, float* __restrict__ out, float* __restrict__ wspart)
{
    __shared__ float lds[LDS_F];
    const int tid = threadIdx.x;
    const int bid = blockIdx.x;
    const int r0  = bid * TM;
    const int co  = tid & 63;
    const int ro  = tid >> 6;

    // ---- stage x tile (32 rows x 16 quads), row-swizzled ----
    {
        const float4* xg = (const float4*)(x + (long long)r0 * IND);
        float4* xs = (float4*)&lds[0];
#pragma unroll
        for (int i = 0; i < 2; ++i) {
            int f4 = tid + 256 * i;
            int row = f4 >> 4, q = f4 & 15;
            xs[row * 16 + (q ^ (row & 7))] = xg[f4];
        }
    }
    __syncthreads();

    float acc[8][4];

    // ---- GEMM1: h1 = gelu(x @ W1^T + b1), K=64 ----
#pragma unroll
    for (int i = 0; i < 8; ++i)
#pragma unroll
        for (int j = 0; j < 4; ++j) acc[i][j] = 0.f;
    for (int kk = 0; kk < IND; kk += 4) {
        const int kq = kk >> 2;
        float4 hv[8];
#pragma unroll
        for (int i = 0; i < 8; ++i)
            hv[i] = *(const float4*)&lds[(8 * ro + i) * IND + 4 * (kq ^ i)];
#pragma unroll
        for (int j = 0; j < 4; ++j) {
            float4 wv = *(const float4*)&W1[(4 * co + j) * IND + kk];
#pragma unroll
            for (int i = 0; i < 8; ++i) acc[i][j] += dot4(hv[i], wv);
        }
    }
    __syncthreads();  // x reads done; overwrite with h1 (row-swizzled quads)
    {
        float4 bb = *(const float4*)&b1[4 * co];
#pragma unroll
        for (int i = 0; i < 8; ++i) {
            float4 h;
            h.x = gelu_f(acc[i][0] + bb.x);
            h.y = gelu_f(acc[i][1] + bb.y);
            h.z = gelu_f(acc[i][2] + bb.z);
            h.w = gelu_f(acc[i][3] + bb.w);
            *(float4*)&lds[(8 * ro + i) * HD + 4 * (co ^ i)] = h;
        }
    }
    __syncthreads();

    // ---- GEMM2: h2 = gelu(h1 @ W2^T + b2), K=256, acc in regs ----
#pragma unroll
    for (int i = 0; i < 8; ++i)
#pragma unroll
        for (int j = 0; j < 4; ++j) acc[i][j] = 0.f;
    for (int kk = 0; kk < HD; kk += 4) {
        const int kq = kk >> 2;
        float4 hv[8];
#pragma unroll
        for (int i = 0; i < 8; ++i)
            hv[i] = *(const float4*)&lds[(8 * ro + i) * HD + 4 * (kq ^ i)];
#pragma unroll
        for (int j = 0; j < 4; ++j) {
            float4 wv = *(const float4*)&W2[(4 * co + j) * HD + kk];
#pragma unroll
            for (int i = 0; i < 8; ++i) acc[i][j] += dot4(hv[i], wv);
        }
    }
    __syncthreads();  // h1 reads done; overwrite with h2 (same swizzle)
    {
        float4 bb = *(const float4*)&b2[4 * co];
#pragma unroll
        for (int i = 0; i < 8; ++i) {
            float4 h;
            h.x = gelu_f(acc[i][0] + bb.x);
            h.y = gelu_f(acc[i][1] + bb.y);
            h.z = gelu_f(acc[i][2] + bb.z);
            h.w = gelu_f(acc[i][3] + bb.w);
            *(float4*)&lds[(8 * ro + i) * HD + 4 * (co ^ i)] = h;
        }
    }
    __syncthreads();

    // ---- phase 3: scores (folded M) + v, softmax, argmax ----
    const int r  = tid >> 3;        // 0..31
    const int s  = tid & 7;         // 0..7 (chart lane)
    const int rx = r & 7;
    const long long b = r0 + r;

    float  accS = 0.f;
    float4 accV; accV.x = accV.y = accV.z = accV.w = 0.f;
    const float* Mrow = ws + WS_M + s * HD;
    for (int k4 = 0; k4 < 64; ++k4) {
        float4 hv = *(const float4*)&lds[r * HD + 4 * (k4 ^ rx)];
        float4 mv = *(const float4*)&Mrow[4 * k4];
        accS += dot4(hv, mv);
        float4 q0 = *(const float4*)&Wv[(4 * s + 0) * HD + 4 * k4];
        float4 q1 = *(const float4*)&Wv[(4 * s + 1) * HD + 4 * k4];
        float4 q2 = *(const float4*)&Wv[(4 * s + 2) * HD + 4 * k4];
        float4 q3 = *(const float4*)&Wv[(4 * s + 3) * HD + 4 * k4];
        accV.x += dot4(hv, q0);
        accV.y += dot4(hv, q1);
        accV.z += dot4(hv, q2);
        accV.w += dot4(hv, q3);
    }
    float score = (accS + ws[WS_C0 + s]) * (1.0f / 16.0f);
    float mx = score;
    mx = fmaxf(mx, __shfl_xor(mx, 1, 64));
    mx = fmaxf(mx, __shfl_xor(mx, 2, 64));
    mx = fmaxf(mx, __shfl_xor(mx, 4, 64));
    float e = expf(score - mx);
    float sm = e;
    sm += __shfl_xor(sm, 1, 64);
    sm += __shfl_xor(sm, 2, 64);
    sm += __shfl_xor(sm, 4, 64);
    const float w_reg = e / sm;
    out[O_RW + b * 8 + s] = w_reg;
    float av = e; int ai = s;
    {
        float ov; int oi;
        ov = __shfl_xor(av, 1, 64); oi = __shfl_xor(ai, 1, 64);
        if (ov > av || (ov == av && oi < ai)) { av = ov; ai = oi; }
        ov = __shfl_xor(av, 2, 64); oi = __shfl_xor(ai, 2, 64);
        if (ov > av || (ov == av && oi < ai)) { av = ov; ai = oi; }
        ov = __shfl_xor(av, 4, 64); oi = __shfl_xor(ai, 4, 64);
        if (ov > av || (ov == av && oi < ai)) { av = ov; ai = oi; }
    }
    const int kchart = ai;
    if (s == 0) out[O_KCHART + b] = (float)kchart;

    __syncthreads();  // ALL h2 reads done; region A free for overlay

    // ---- write v (overlay region), stage s-net weights ----
    {
        float4 bb = *(const float4*)&bv[4 * s];
        float4 vv;
        vv.x = accV.x + bb.x; vv.y = accV.y + bb.y;
        vv.z = accV.z + bb.z; vv.w = accV.w + bb.w;
        *(float4*)&lds[L_VDL + r * 36 + 4 * s] = vv;
    }
#pragma unroll
    for (int it = 0; it < 2; ++it) {
        int idx = tid + 256 * it;
        lds[L_W1 + (idx >> 5) * 36 + (idx & 31)] = Ws1[idx];        // 16x32, stride 36
        lds[L_W2 + (idx & 15) * 36 + (idx >> 4)] = Ws2[idx];        // W2T[j][o], stride 36
    }
    if (tid < 16) lds[L_B1 + tid] = bs1[tid];
    if (tid < 32) lds[L_B2 + tid] = bs2[tid];

    // v row preload (same-wave data; no barrier needed)
    float4 v4[8];
#pragma unroll
    for (int j = 0; j < 8; ++j)
        v4[j] = *(const float4*)&lds[L_VDL + r * 36 + 4 * j];
    const float4 vs = v4[s];

    float vsq32;
    {
        float vr[32];
#pragma unroll
        for (int j = 0; j < 8; ++j) {
            vr[4 * j + 0] = v4[j].x; vr[4 * j + 1] = v4[j].y;
            vr[4 * j + 2] = v4[j].z; vr[4 * j + 3] = v4[j].w;
        }
        vsq32 = np_sumsq32(vr);
    }

    float4 zqb; zqb.x = zqb.y = zqb.z = zqb.w = 0.f;
    float4 zn4; zn4.x = zn4.y = zn4.z = zn4.w = 0.f;
    float lossAcc = 0.f;
    int kcode = 0;

    const float4* cb_l = (const float4*)&lds[L_CH];

    for (int n = 0; n < NCH; ++n) {
        const float* csqn = ws + WS_CSQ + n * NCD;
        float b1v = 3.4e38f, b2v = 3.4e38f;
        int   i1c = 0,       i2c = 0;

#pragma unroll
        for (int h = 0; h < 2; ++h) {
            __syncthreads();  // prev scan reads of L_CH done (and weights/v visible at n=0)
            // stage half-chart (128 codes x 32) swizzled
            {
                const float4* cbg = (const float4*)(cb + ((long long)n * NCD + h * 128) * LT);
                float4* dst = (float4*)&lds[L_CH];
#pragma unroll
                for (int i = 0; i < 4; ++i) {
                    int f4 = tid + 256 * i;
                    int cl = f4 >> 3, j = f4 & 7;
                    dst[cl * 8 + (j ^ (cl & 7))] = cbg[f4];
                }
            }
            __syncthreads();

            // ---- approx scan half h: top-2 by dist' = c_sq - 2*v.c ----
            const int cbase = h * 128;
            for (int i = 0; i < 16; i += 2) {
                const int cl0 = (i << 3) + s;     // cl0 & 7 == s
                const int cl1 = cl0 + 8;
                const float4* p0 = cb_l + cl0 * 8;
                const float4* p1 = cb_l + cl1 * 8;
                float da0 = 0.f, db0 = 0.f, da1 = 0.f, db1 = 0.f;
#pragma unroll
                for (int j = 0; j < 4; ++j) {
                    da0 += dot4(p0[j ^ s], v4[j]);
                    da1 += dot4(p1[j ^ s], v4[j]);
                }
#pragma unroll
                for (int j = 4; j < 8; ++j) {
                    db0 += dot4(p0[j ^ s], v4[j]);
                    db1 += dot4(p1[j ^ s], v4[j]);
                }
                const int c0 = cbase + cl0;
                const int c1 = cbase + cl1;
                float d0 = csqn[c0] - 2.f * (da0 + db0);
                float d1 = csqn[c1] - 2.f * (da1 + db1);
                if (d0 < b1v)      { b2v = b1v; i2c = i1c; b1v = d0; i1c = c0; }
                else if (d0 < b2v) { b2v = d0; i2c = c0; }
                if (d1 < b1v)      { b2v = b1v; i2c = i1c; b1v = d1; i1c = c1; }
                else if (d1 < b2v) { b2v = d1; i2c = c1; }
            }
        }

        // cross-lane top-2 merge over the row's 8 lanes
#pragma unroll
        for (int off = 1; off < 8; off <<= 1) {
            float o1 = __shfl_xor(b1v, off, 64); int oi1 = __shfl_xor(i1c, off, 64);
            float o2 = __shfl_xor(b2v, off, 64); int oi2 = __shfl_xor(i2c, off, 64);
            if (o1 < b1v || (o1 == b1v && oi1 < i1c)) {
                float nb2; int ni2;
                if (b1v < o2 || (b1v == o2 && i1c < oi2)) { nb2 = b1v; ni2 = i1c; }
                else                                      { nb2 = o2;  ni2 = oi2; }
                b1v = o1; i1c = oi1; b2v = nb2; i2c = ni2;
            } else if (o1 < b2v || (o1 == b2v && oi1 < i2c)) {
                b2v = o1; i2c = oi1;
            }
        }

        // ---- exact re-eval of top-2 (rows from GLOBAL, L2-hot): fp64 cross,
        //      reference-exact fp32 combine, lower-index tie-break ----
        int bestC;
        {
            const int cand = (s & 1) ? i2c : i1c;
            const float4* pc = (const float4*)(cb + ((long long)n * NCD + cand) * LT);
            double cr = 0.0;
#pragma unroll
            for (int j = 0; j < 8; ++j) {
                float4 q = pc[j];
                float4 vv = v4[j];
                cr += (double)vv.x * q.x + (double)vv.y * q.y
                    + (double)vv.z * q.z + (double)vv.w * q.w;
            }
            float cross32 = (float)cr;
            float dme;
            {
#pragma clang fp contract(off)
                dme = (vsq32 - 2.0f * cross32) + csqn[cand];
            }
            float dot_ = __shfl_xor(dme, 1, 64);
            int  candO = __shfl_xor(cand, 1, 64);
            bestC = ((dot_ < dme) || (dot_ == dme && candO < cand)) ? candO : cand;
        }

        if (s == 0) out[O_IDX + b * 8 + n] = (float)bestC;
        if (n == kchart) kcode = bestC;

        const float wn = __shfl(w_reg, (tid & 56) | n, 64);

        // z_q quad s from global (same 128B line per row-group, L2-hot)
        float4 zq = *(const float4*)(cb + ((long long)n * NCD + bestC) * LT + 4 * s);
        float4 d4;
        d4.x = vs.x - zq.x; d4.y = vs.y - zq.y;
        d4.z = vs.z - zq.z; d4.w = vs.w - zq.w;
        lossAcc += wn * (d4.x * d4.x + d4.y * d4.y + d4.z * d4.z + d4.w * d4.w);
        zqb.x += wn * zq.x; zqb.y += wn * zq.y;
        zqb.z += wn * zq.z; zqb.w += wn * zq.w;
        *(float4*)&lds[L_VDL + r * 36 + 4 * s] = d4;   // delta row (v stays in regs)

        // s-net layer 1 (same-wave delta; weights in LDS, stride-36)
        float a0 = lds[L_B1 + s], a1 = lds[L_B1 + s + 8];
#pragma unroll
        for (int q = 0; q < 8; ++q) {
            float4 dq = *(const float4*)&lds[L_VDL + r * 36 + 4 * q];
            float4 u0 = *(const float4*)&lds[L_W1 + s * 36 + 4 * q];
            float4 u1 = *(const float4*)&lds[L_W1 + (s + 8) * 36 + 4 * q];
            a0 += dot4(dq, u0);
            a1 += dot4(dq, u1);
        }
        lds[L_S1 + r * 20 + s]     = gelu_f(a0);
        lds[L_S1 + r * 20 + s + 8] = gelu_f(a1);

        // s-net layer 2 via transposed W2: zna(quad 4s) += s1[j] * W2T[j][4s..4s+3]
        float4 sv0 = *(const float4*)&lds[L_S1 + r * 20 + 0];
        float4 sv1 = *(const float4*)&lds[L_S1 + r * 20 + 4];
        float4 sv2 = *(const float4*)&lds[L_S1 + r * 20 + 8];
        float4 sv3 = *(const float4*)&lds[L_S1 + r * 20 + 12];
        float4 zna = *(const float4*)&lds[L_B2 + 4 * s];
        const float s1v[16] = { sv0.x, sv0.y, sv0.z, sv0.w, sv1.x, sv1.y, sv1.z, sv1.w,
                                sv2.x, sv2.y, sv2.z, sv2.w, sv3.x, sv3.y, sv3.z, sv3.w };
#pragma unroll
        for (int j = 0; j < 16; ++j) {
            float4 wj = *(const float4*)&lds[L_W2 + j * 36 + 4 * s];
            zna.x += s1v[j] * wj.x; zna.y += s1v[j] * wj.y;
            zna.z += s1v[j] * wj.z; zna.w += s1v[j] * wj.w;
        }
        zn4.x += wn * zna.x; zn4.y += wn * zna.y;
        zn4.z += wn * zna.z; zn4.w += wn * zna.w;
        *(float4*)&out[O_ZNALL + (b * 8 + n) * 32 + 4 * s] = zna;
    }

    // ---- final per-row outputs (lane s owns quad s) ----
    {
        float4 zt, zg;
        zt.x = (vs.x - zqb.x) - zn4.x; zt.y = (vs.y - zqb.y) - zn4.y;
        zt.z = (vs.z - zqb.z) - zn4.z; zt.w = (vs.w - zqb.w) - zn4.w;
        zg.x = zqb.x + zn4.x; zg.y = zqb.y + zn4.y;
        zg.z = zqb.z + zn4.z; zg.w = zqb.w + zn4.w;
        *(float4*)&out[O_ZN   + b * 32 + 4 * s] = zn4;
        *(float4*)&out[O_ZTEX + b * 32 + 4 * s] = zt;
        *(float4*)&out[O_ZGEO + b * 32 + 4 * s] = zg;
        if (s == 0) out[O_KCODE + b] = (float)kcode;
    }

    // ---- block loss partial ----
#pragma unroll
    for (int off = 1; off < 64; off <<= 1) lossAcc += __shfl_xor(lossAcc, off, 64);
    __syncthreads();
    if ((tid & 63) == 0) lds[L_MISC + (tid >> 6)] = lossAcc;
    __syncthreads();
    if (tid == 0)
        wspart[bid] = lds[L_MISC] + lds[L_MISC+1] + lds[L_MISC+2] + lds[L_MISC+3];
}

// ---------- finalize vq_loss ----------
__global__ __launch_bounds__(256) void fin_kernel(const float* __restrict__ wspart,
                                                  float* __restrict__ out)
{
    const int t = threadIdx.x;
    float sum = 0.f;
    for (int i = t; i < NBLK; i += 256) sum += wspart[i];
#pragma unroll
    for (int off = 1; off < 64; off <<= 1) sum += __shfl_xor(sum, off, 64);
    __shared__ float red[4];
    if ((t & 63) == 0) red[t >> 6] = sum;
    __syncthreads();
    if (t == 0)
        out[O_VQ] = (red[0] + red[1] + red[2] + red[3]) * (1.25f / (32768.0f * 32.0f));
}

extern "C" void kernel_launch(void* const* d_in, const int* in_sizes, int n_in,
                              void* d_out, int out_size, void* d_ws, size_t ws_size,
                              hipStream_t stream)
{
    const float* x   = (const float*)d_in[0];
    const float* W1  = (const float*)d_in[1];
    const float* b1  = (const float*)d_in[2];
    const float* W2  = (const float*)d_in[3];
    const float* b2  = (const float*)d_in[4];
    const float* Wk  = (const float*)d_in[5];
    const float* bk  = (const float*)d_in[6];
    const float* cq  = (const float*)d_in[7];
    const float* Wv  = (const float*)d_in[8];
    const float* bv  = (const float*)d_in[9];
    const float* cb  = (const float*)d_in[10];
    const float* Ws1 = (const float*)d_in[11];
    const float* bs1 = (const float*)d_in[12];
    const float* Ws2 = (const float*)d_in[13];
    const float* bs2 = (const float*)d_in[14];
    float* out = (float*)d_out;
    float* ws  = (float*)d_ws;

    prep_kernel<<<8, 256, 0, stream>>>(Wk, bk, cq, cb, ws);
    main_kernel<<<NBLK, 256, 0, stream>>>(x, W1, b1, W2, b2, Wv, bv, cb,
                                          Ws1, bs1, Ws2, bs2, ws, out, ws + WS_PART);
    fin_kernel<<<1, 256, 0, stream>>>(ws + WS_PART, out);
}

// Round 7
// 629.121 us; speedup vs baseline: 1.9016x; 1.9016x over previous
//
#include <hip/hip_runtime.h>
#include <math.h>

static constexpr int BTOT = 32768;
static constexpr int IND  = 64;
static constexpr int HD   = 256;
static constexpr int LT   = 32;
static constexpr int NCH  = 8;
static constexpr int NCD  = 256;
static constexpr int TM   = 32;
static constexpr int NBLK = BTOT / TM;   // 1024

// workspace float offsets
static constexpr int WS_M    = 0;        // 8*256 folded score matrix M = cq@Wk
static constexpr int WS_C0   = 2048;     // 8 folded score bias c0 = cq@bk
static constexpr int WS_CSQ  = 2056;     // 8*256 codebook squared norms (np-pairwise fp32)
static constexpr int WS_PART = 4104;     // NBLK loss partials

// output float offsets
static constexpr long long O_KCHART = 0;
static constexpr long long O_KCODE  = 32768;
static constexpr long long O_ZN     = 65536;
static constexpr long long O_ZTEX   = 1114112;
static constexpr long long O_RW     = 2162688;
static constexpr long long O_ZGEO   = 2424832;
static constexpr long long O_VQ     = 3473408;
static constexpr long long O_IDX    = 3473409;
static constexpr long long O_ZNALL  = 3735553;

// LDS: 9408 floats = 36.75 KB -> 4 blocks/CU when VGPR<=128.
// [0..8192): x(swz) -> h1(swz) -> h2(swz) -> chart n (swz). No other overlays.
static constexpr int L_CH  = 0;
static constexpr int L_W1  = 8192;   // 16 rows x stride 36: Ws1
static constexpr int L_W2T = 8768;   // 16 rows x stride 36: Ws2 transposed (W2T[k][o])
static constexpr int L_B1  = 9344;   // 16
static constexpr int L_B2  = 9360;   // 32
static constexpr int L_MISC= 9392;   // 16: loss reduce scratch
static constexpr int LDS_F = 9408;

__device__ __forceinline__ float gelu_f(float x) {
    return 0.5f * x * (1.0f + erff(x * 0.70710678118654752f));
}
__device__ __forceinline__ float dot4(float4 a, float4 b) {
    return a.x * b.x + a.y * b.y + a.z * b.z + a.w * b.w;
}
// numpy pairwise_sum of squares, n=32 (8 accumulators, stride-8, fixed tree)
__device__ __forceinline__ float np_sumsq32(const float* a) {
#pragma clang fp contract(off)
    float r0 = a[0]*a[0],  r1 = a[1]*a[1],  r2 = a[2]*a[2],  r3 = a[3]*a[3];
    float r4 = a[4]*a[4],  r5 = a[5]*a[5],  r6 = a[6]*a[6],  r7 = a[7]*a[7];
    r0 += a[8]*a[8];   r1 += a[9]*a[9];   r2 += a[10]*a[10]; r3 += a[11]*a[11];
    r4 += a[12]*a[12]; r5 += a[13]*a[13]; r6 += a[14]*a[14]; r7 += a[15]*a[15];
    r0 += a[16]*a[16]; r1 += a[17]*a[17]; r2 += a[18]*a[18]; r3 += a[19]*a[19];
    r4 += a[20]*a[20]; r5 += a[21]*a[21]; r6 += a[22]*a[22]; r7 += a[23]*a[23];
    r0 += a[24]*a[24]; r1 += a[25]*a[25]; r2 += a[26]*a[26]; r3 += a[27]*a[27];
    r4 += a[28]*a[28]; r5 += a[29]*a[29]; r6 += a[30]*a[30]; r7 += a[31]*a[31];
    return ((r0 + r1) + (r2 + r3)) + ((r4 + r5) + (r6 + r7));
}

// ---------- prep (16 blocks): M rows coalesced, c_sq, c0 ----------
__global__ __launch_bounds__(256) void prep_kernel(
    const float* __restrict__ Wk, const float* __restrict__ bk,
    const float* __restrict__ cq, const float* __restrict__ cb,
    float* __restrict__ ws)
{
    const int g = blockIdx.x;
    const int t = threadIdx.x;
    if (g < 8) {
        // M[g][t] = sum_o cq[g][o]*Wk[o][t]; per-o loads coalesced across lanes.
        // Same per-element FP order as prior passing rounds.
        float acc = 0.f;
        for (int o = 0; o < HD; ++o)
            acc += cq[g * HD + o] * Wk[o * HD + t];
        ws[WS_M + g * HD + t] = acc;
    } else {
        const int gg = g - 8;
        {
            const float* p = cb + (long long)((gg << 8) + t) * LT;
            float a[32];
#pragma unroll
            for (int d = 0; d < LT; ++d) a[d] = p[d];
            ws[WS_CSQ + (gg << 8) + t] = np_sumsq32(a);
        }
        {
            float p = cq[gg * HD + t] * bk[t];
#pragma unroll
            for (int off = 1; off < 64; off <<= 1) p += __shfl_xor(p, off, 64);
            __shared__ float red[4];
            if ((t & 63) == 0) red[t >> 6] = p;
            __syncthreads();
            if (t == 0) ws[WS_C0 + gg] = red[0] + red[1] + red[2] + red[3];
        }
    }
}

// ---------- main fused kernel ----------
// Plain __launch_bounds__(256): (256,N) collapses the VGPR budget and spills
// (r3/r4). Waves/SIMD halves past 128 VGPR (r5/r6) — target is VGPR<=128,
// LDS 36.75 KB -> 4 blocks/CU. Chart loop touches LDS only (no global addr
// chains, which is what inflated VGPR in r5/r6).
__global__ __launch_bounds__(256) void main_kernel(
    const float* __restrict__ x,  const float* __restrict__ W1, const float* __restrict__ b1,
    const float* __restrict__ W2, const float* __restrict__ b2,
    const float* __restrict__ Wv, const float* __restrict__ bv,
    const float* __restrict__ cb,
    const float* __restrict__ Ws1, const float* __restrict__ bs1,
    const float* __restrict__ Ws2, const float* __restrict__ bs2,
    const float* __restrict__ ws, float* __restrict__ out, float* __restrict__ wspart)
{
    __shared__ float lds[LDS_F];
    const int tid = threadIdx.x;
    const int bid = blockIdx.x;
    const int r0  = bid * TM;
    const int co  = tid & 63;
    const int ro  = tid >> 6;

    // ---- stage x tile (swizzled) + s-net weights (conflict-free strides) ----
    {
        const float4* xg = (const float4*)(x + (long long)r0 * IND);
        float4* xs = (float4*)&lds[L_CH];
#pragma unroll
        for (int i = 0; i < 2; ++i) {
            int f4 = tid + 256 * i;
            int row = f4 >> 4, q = f4 & 15;
            xs[row * 16 + (q ^ (row & 7))] = xg[f4];
        }
    }
#pragma unroll
    for (int it = 0; it < 2; ++it) {
        int idx = tid + 256 * it;
        lds[L_W1  + (idx >> 5) * 36 + (idx & 31)] = Ws1[idx];   // Ws1[j][k]
        lds[L_W2T + (idx & 15) * 36 + (idx >> 4)] = Ws2[idx];   // W2T[k][o]
    }
    if (tid < 16) lds[L_B1 + tid] = bs1[tid];
    if (tid < 32) lds[L_B2 + tid] = bs2[tid];
    __syncthreads();

    float acc[8][4];

    // ---- GEMM1: h1 = gelu(x @ W1^T + b1), K=64 ----
#pragma unroll
    for (int i = 0; i < 8; ++i)
#pragma unroll
        for (int j = 0; j < 4; ++j) acc[i][j] = 0.f;
    for (int kk = 0; kk < IND; kk += 4) {
        const int kq = kk >> 2;
        float4 hv[8];
#pragma unroll
        for (int i = 0; i < 8; ++i)
            hv[i] = *(const float4*)&lds[L_CH + (8 * ro + i) * IND + 4 * (kq ^ i)];
#pragma unroll
        for (int j = 0; j < 4; ++j) {
            float4 wv = *(const float4*)&W1[(4 * co + j) * IND + kk];
#pragma unroll
            for (int i = 0; i < 8; ++i) acc[i][j] += dot4(hv[i], wv);
        }
    }
    __syncthreads();  // x reads done; overwrite with h1 (row-swizzled quads)
    {
        float4 bb = *(const float4*)&b1[4 * co];
#pragma unroll
        for (int i = 0; i < 8; ++i) {
            float4 h;
            h.x = gelu_f(acc[i][0] + bb.x);
            h.y = gelu_f(acc[i][1] + bb.y);
            h.z = gelu_f(acc[i][2] + bb.z);
            h.w = gelu_f(acc[i][3] + bb.w);
            *(float4*)&lds[L_CH + (8 * ro + i) * HD + 4 * (co ^ i)] = h;
        }
    }
    __syncthreads();

    // ---- GEMM2: h2 = gelu(h1 @ W2^T + b2), K=256, acc in regs ----
#pragma unroll
    for (int i = 0; i < 8; ++i)
#pragma unroll
        for (int j = 0; j < 4; ++j) acc[i][j] = 0.f;
    for (int kk = 0; kk < HD; kk += 4) {
        const int kq = kk >> 2;
        float4 hv[8];
#pragma unroll
        for (int i = 0; i < 8; ++i)
            hv[i] = *(const float4*)&lds[L_CH + (8 * ro + i) * HD + 4 * (kq ^ i)];
#pragma unroll
        for (int j = 0; j < 4; ++j) {
            float4 wv = *(const float4*)&W2[(4 * co + j) * HD + kk];
#pragma unroll
            for (int i = 0; i < 8; ++i) acc[i][j] += dot4(hv[i], wv);
        }
    }
    __syncthreads();  // h1 reads done; overwrite with h2 (same swizzle)
    {
        float4 bb = *(const float4*)&b2[4 * co];
#pragma unroll
        for (int i = 0; i < 8; ++i) {
            float4 h;
            h.x = gelu_f(acc[i][0] + bb.x);
            h.y = gelu_f(acc[i][1] + bb.y);
            h.z = gelu_f(acc[i][2] + bb.z);
            h.w = gelu_f(acc[i][3] + bb.w);
            *(float4*)&lds[L_CH + (8 * ro + i) * HD + 4 * (co ^ i)] = h;
        }
    }
    __syncthreads();

    // ---- phase 3: scores (folded M) + v, softmax, argmax ----
    const int r  = tid >> 3;        // 0..31
    const int s  = tid & 7;         // 0..7 (chart lane)
    const int rx = r & 7;
    const long long b = r0 + r;

    float  accS = 0.f;
    float4 accV; accV.x = accV.y = accV.z = accV.w = 0.f;
    const float* Mrow = ws + WS_M + s * HD;
    for (int k4 = 0; k4 < 64; ++k4) {
        float4 hv = *(const float4*)&lds[L_CH + r * HD + 4 * (k4 ^ rx)];
        float4 mv = *(const float4*)&Mrow[4 * k4];
        accS += dot4(hv, mv);
        float4 q0 = *(const float4*)&Wv[(4 * s + 0) * HD + 4 * k4];
        float4 q1 = *(const float4*)&Wv[(4 * s + 1) * HD + 4 * k4];
        float4 q2 = *(const float4*)&Wv[(4 * s + 2) * HD + 4 * k4];
        float4 q3 = *(const float4*)&Wv[(4 * s + 3) * HD + 4 * k4];
        accV.x += dot4(hv, q0);
        accV.y += dot4(hv, q1);
        accV.z += dot4(hv, q2);
        accV.w += dot4(hv, q3);
    }
    float score = (accS + ws[WS_C0 + s]) * (1.0f / 16.0f);
    float mx = score;
    mx = fmaxf(mx, __shfl_xor(mx, 1, 64));
    mx = fmaxf(mx, __shfl_xor(mx, 2, 64));
    mx = fmaxf(mx, __shfl_xor(mx, 4, 64));
    float e = expf(score - mx);
    float sm = e;
    sm += __shfl_xor(sm, 1, 64);
    sm += __shfl_xor(sm, 2, 64);
    sm += __shfl_xor(sm, 4, 64);
    const float w_reg = e / sm;
    out[O_RW + b * 8 + s] = w_reg;
    float av = e; int ai = s;
    {
        float ov; int oi;
        ov = __shfl_xor(av, 1, 64); oi = __shfl_xor(ai, 1, 64);
        if (ov > av || (ov == av && oi < ai)) { av = ov; ai = oi; }
        ov = __shfl_xor(av, 2, 64); oi = __shfl_xor(ai, 2, 64);
        if (ov > av || (ov == av && oi < ai)) { av = ov; ai = oi; }
        ov = __shfl_xor(av, 4, 64); oi = __shfl_xor(ai, 4, 64);
        if (ov > av || (ov == av && oi < ai)) { av = ov; ai = oi; }
    }
    const int kchart = ai;
    if (s == 0) out[O_KCHART + b] = (float)kchart;

    // ---- v row gathered into registers via shuffles (no LDS) ----
    float4 v4[8];
    {
        float4 bb = *(const float4*)&bv[4 * s];
        float4 vv;
        vv.x = accV.x + bb.x; vv.y = accV.y + bb.y;
        vv.z = accV.z + bb.z; vv.w = accV.w + bb.w;
        const int base = tid & 56;
#pragma unroll
        for (int j = 0; j < 8; ++j) {
            const int src = base | j;
            v4[j].x = __shfl(vv.x, src, 64);
            v4[j].y = __shfl(vv.y, src, 64);
            v4[j].z = __shfl(vv.z, src, 64);
            v4[j].w = __shfl(vv.w, src, 64);
        }
    }
    const float4 vs = v4[s];

    float vsq32;
    {
        float vr[32];
#pragma unroll
        for (int j = 0; j < 8; ++j) {
            vr[4 * j + 0] = v4[j].x; vr[4 * j + 1] = v4[j].y;
            vr[4 * j + 2] = v4[j].z; vr[4 * j + 3] = v4[j].w;
        }
        vsq32 = np_sumsq32(vr);
    }

    float4 zqb; zqb.x = zqb.y = zqb.z = zqb.w = 0.f;
    float4 zn4; zn4.x = zn4.y = zn4.z = zn4.w = 0.f;
    float lossAcc = 0.f;
    int kcode = 0;

    const float4* cb_l = (const float4*)&lds[L_CH];

    for (int n = 0; n < NCH; ++n) {
        __syncthreads();  // prev chart readers (and for n=0, h2 readers) done
        // stage chart n (256x32) into L_CH, xor-swizzled quads
        {
            const float4* cbg = (const float4*)(cb + (long long)n * NCD * LT);
            float4* dst = (float4*)&lds[L_CH];
#pragma unroll
            for (int i = 0; i < 8; ++i) {
                int f4 = tid + 256 * i;
                int c = f4 >> 3, j = f4 & 7;
                dst[c * 8 + (j ^ (c & 7))] = cbg[f4];
            }
        }
        __syncthreads();

        // ---- approx scan: track top-2 by dist' = c_sq - 2*v.c ----
        const float* csqn = ws + WS_CSQ + n * NCD;
        float b1v = 3.4e38f, b2v = 3.4e38f;
        int   i1c = 0,       i2c = 0;
        for (int i = 0; i < 32; i += 2) {
            const int c0 = (i << 3) + s;           // c0 & 7 == s
            const int c1 = c0 + 8;
            const float4* p0 = cb_l + c0 * 8;
            const float4* p1 = cb_l + c1 * 8;
            float da0 = 0.f, db0 = 0.f, da1 = 0.f, db1 = 0.f;
#pragma unroll
            for (int j = 0; j < 4; ++j) {
                da0 += dot4(p0[j ^ s], v4[j]);
                da1 += dot4(p1[j ^ s], v4[j]);
            }
#pragma unroll
            for (int j = 4; j < 8; ++j) {
                db0 += dot4(p0[j ^ s], v4[j]);
                db1 += dot4(p1[j ^ s], v4[j]);
            }
            float d0 = csqn[c0] - 2.f * (da0 + db0);
            float d1 = csqn[c1] - 2.f * (da1 + db1);
            if (d0 < b1v)      { b2v = b1v; i2c = i1c; b1v = d0; i1c = c0; }
            else if (d0 < b2v) { b2v = d0; i2c = c0; }
            if (d1 < b1v)      { b2v = b1v; i2c = i1c; b1v = d1; i1c = c1; }
            else if (d1 < b2v) { b2v = d1; i2c = c1; }
        }
        // cross-lane top-2 merge over the row's 8 lanes
#pragma unroll
        for (int off = 1; off < 8; off <<= 1) {
            float o1 = __shfl_xor(b1v, off, 64); int oi1 = __shfl_xor(i1c, off, 64);
            float o2 = __shfl_xor(b2v, off, 64); int oi2 = __shfl_xor(i2c, off, 64);
            if (o1 < b1v || (o1 == b1v && oi1 < i1c)) {
                float nb2; int ni2;
                if (b1v < o2 || (b1v == o2 && i1c < oi2)) { nb2 = b1v; ni2 = i1c; }
                else                                      { nb2 = o2;  ni2 = oi2; }
                b1v = o1; i1c = oi1; b2v = nb2; i2c = ni2;
            } else if (o1 < b2v || (o1 == b2v && oi1 < i2c)) {
                b2v = o1; i2c = oi1;
            }
        }

        // ---- exact re-eval of top-2: fp64 cross, reference-exact fp32 combine ----
        int bestC;
        {
            const int cand = (s & 1) ? i2c : i1c;
            const int cx = cand & 7;
            double cr = 0.0;
            const float4* pc = cb_l + cand * 8;
#pragma unroll
            for (int j = 0; j < 8; ++j) {
                float4 q = pc[j ^ cx];
                float4 vv = v4[j];
                cr += (double)vv.x * q.x + (double)vv.y * q.y
                    + (double)vv.z * q.z + (double)vv.w * q.w;
            }
            float cross32 = (float)cr;
            float dme;
            {
#pragma clang fp contract(off)
                dme = (vsq32 - 2.0f * cross32) + csqn[cand];
            }
            float dot_ = __shfl_xor(dme, 1, 64);
            int  candO = __shfl_xor(cand, 1, 64);
            bestC = ((dot_ < dme) || (dot_ == dme && candO < cand)) ? candO : cand;
        }

        if (s == 0) out[O_IDX + b * 8 + n] = (float)bestC;
        if (n == kchart) kcode = bestC;

        const float wn = __shfl(w_reg, (tid & 56) | n, 64);
        const int bswz = bestC & 7;

        // own-quad z_q -> delta, loss, blend accumulators
        {
            float4 zq = *(const float4*)&lds[L_CH + bestC * 32 + 4 * (s ^ bswz)];
            float4 d4;
            d4.x = vs.x - zq.x; d4.y = vs.y - zq.y;
            d4.z = vs.z - zq.z; d4.w = vs.w - zq.w;
            lossAcc += wn * (d4.x * d4.x + d4.y * d4.y + d4.z * d4.z + d4.w * d4.w);
            zqb.x += wn * zq.x; zqb.y += wn * zq.y;
            zqb.z += wn * zq.z; zqb.w += wn * zq.w;
        }

        // s-net layer 1: delta computed on the fly (v4[q] - zq[q]); no LDS scratch
        float s1a, s1b;
        {
            float a0 = lds[L_B1 + s], a1 = lds[L_B1 + s + 8];
#pragma unroll
            for (int q = 0; q < 8; ++q) {
                float4 zq = *(const float4*)&lds[L_CH + bestC * 32 + 4 * (q ^ bswz)];
                float4 dq;
                dq.x = v4[q].x - zq.x; dq.y = v4[q].y - zq.y;
                dq.z = v4[q].z - zq.z; dq.w = v4[q].w - zq.w;
                float4 u0 = *(const float4*)&lds[L_W1 + s * 36 + 4 * q];
                float4 u1 = *(const float4*)&lds[L_W1 + (s + 8) * 36 + 4 * q];
                a0 += dot4(dq, u0);
                a1 += dot4(dq, u1);
            }
            s1a = gelu_f(a0);
            s1b = gelu_f(a1);
        }

        // s-net layer 2: s1 shared via shuffles, W2T stride-36 (conflict-free)
        float4 zna = *(const float4*)&lds[L_B2 + 4 * s];
        {
            const int base = tid & 56;
#pragma unroll
            for (int j = 0; j < 8; ++j) {
                float sj = __shfl(s1a, base | j, 64);
                float4 wj = *(const float4*)&lds[L_W2T + j * 36 + 4 * s];
                zna.x += sj * wj.x; zna.y += sj * wj.y;
                zna.z += sj * wj.z; zna.w += sj * wj.w;
            }
#pragma unroll
            for (int j = 0; j < 8; ++j) {
                float sj = __shfl(s1b, base | j, 64);
                float4 wj = *(const float4*)&lds[L_W2T + (j + 8) * 36 + 4 * s];
                zna.x += sj * wj.x; zna.y += sj * wj.y;
                zna.z += sj * wj.z; zna.w += sj * wj.w;
            }
        }
        zn4.x += wn * zna.x; zn4.y += wn * zna.y;
        zn4.z += wn * zna.z; zn4.w += wn * zna.w;
        *(float4*)&out[O_ZNALL + (b * 8 + n) * 32 + 4 * s] = zna;
    }

    // ---- final per-row outputs (lane s owns quad s) ----
    {
        float4 zt, zg;
        zt.x = (vs.x - zqb.x) - zn4.x; zt.y = (vs.y - zqb.y) - zn4.y;
        zt.z = (vs.z - zqb.z) - zn4.z; zt.w = (vs.w - zqb.w) - zn4.w;
        zg.x = zqb.x + zn4.x; zg.y = zqb.y + zn4.y;
        zg.z = zqb.z + zn4.z; zg.w = zqb.w + zn4.w;
        *(float4*)&out[O_ZN   + b * 32 + 4 * s] = zn4;
        *(float4*)&out[O_ZTEX + b * 32 + 4 * s] = zt;
        *(float4*)&out[O_ZGEO + b * 32 + 4 * s] = zg;
        if (s == 0) out[O_KCODE + b] = (float)kcode;
    }

    // ---- block loss partial ----
#pragma unroll
    for (int off = 1; off < 64; off <<= 1) lossAcc += __shfl_xor(lossAcc, off, 64);
    __syncthreads();
    if ((tid & 63) == 0) lds[L_MISC + (tid >> 6)] = lossAcc;
    __syncthreads();
    if (tid == 0)
        wspart[bid] = lds[L_MISC] + lds[L_MISC+1] + lds[L_MISC+2] + lds[L_MISC+3];
}

// ---------- finalize vq_loss ----------
__global__ __launch_bounds__(256) void fin_kernel(const float* __restrict__ wspart,
                                                  float* __restrict__ out)
{
    const int t = threadIdx.x;
    float sum = 0.f;
    for (int i = t; i < NBLK; i += 256) sum += wspart[i];
#pragma unroll
    for (int off = 1; off < 64; off <<= 1) sum += __shfl_xor(sum, off, 64);
    __shared__ float red[4];
    if ((t & 63) == 0) red[t >> 6] = sum;
    __syncthreads();
    if (t == 0)
        out[O_VQ] = (red[0] + red[1] + red[2] + red[3]) * (1.25f / (32768.0f * 32.0f));
}

extern "C" void kernel_launch(void* const* d_in, const int* in_sizes, int n_in,
                              void* d_out, int out_size, void* d_ws, size_t ws_size,
                              hipStream_t stream)
{
    const float* x   = (const float*)d_in[0];
    const float* W1  = (const float*)d_in[1];
    const float* b1  = (const float*)d_in[2];
    const float* W2  = (const float*)d_in[3];
    const float* b2  = (const float*)d_in[4];
    const float* Wk  = (const float*)d_in[5];
    const float* bk  = (const float*)d_in[6];
    const float* cq  = (const float*)d_in[7];
    const float* Wv  = (const float*)d_in[8];
    const float* bv  = (const float*)d_in[9];
    const float* cb  = (const float*)d_in[10];
    const float* Ws1 = (const float*)d_in[11];
    const float* bs1 = (const float*)d_in[12];
    const float* Ws2 = (const float*)d_in[13];
    const float* bs2 = (const float*)d_in[14];
    float* out = (float*)d_out;
    float* ws  = (float*)d_ws;

    prep_kernel<<<16, 256, 0, stream>>>(Wk, bk, cq, cb, ws);
    main_kernel<<<NBLK, 256, 0, stream>>>(x, W1, b1, W2, b2, Wv, bv, cb,
                                          Ws1, bs1, Ws2, bs2, ws, out, ws + WS_PART);
    fin_kernel<<<1, 256, 0, stream>>>(ws + WS_PART, out);
}